// Round 1
// baseline (6043.624 us; speedup 1.0000x reference)
//
#include <hip/hip_runtime.h>
#include <hip/hip_bf16.h>

typedef __hip_bfloat16 bf16;
typedef short v8s __attribute__((ext_vector_type(8)));
typedef float v4f __attribute__((ext_vector_type(4)));

__device__ __forceinline__ float cvt(bf16 v) { return __bfloat162float(v); }

__device__ __forceinline__ float ldg_any(const void* p, size_t i, bool bf) {
    return bf ? cvt(((const bf16*)p)[i]) : ((const float*)p)[i];
}
__device__ __forceinline__ void stg_any(void* p, size_t i, float v, bool bf) {
    if (bf) ((bf16*)p)[i] = __float2bfloat16(v);
    else    ((float*)p)[i] = v;
}
__device__ __forceinline__ bool bfmode(int mode, const int* flags) {
    return mode == 2 ? (flags[0] != 0) : (mode != 0);
}
__device__ __forceinline__ unsigned short f2b(float f) {
    bf16 h = __float2bfloat16(f); return *(unsigned short*)&h;
}
__device__ __forceinline__ void b2f2(unsigned u, float& a, float& b) {
    a = __uint_as_float(u << 16);
    b = __uint_as_float(u & 0xffff0000u);
}

// ---------------------------------------------------------------------------
// dtype probe on f3 (N(0,1) data): fp32 never has exponent >= 200.
// ---------------------------------------------------------------------------
__global__ void detect_k(const unsigned int* __restrict__ x, int* __restrict__ flags)
{
    unsigned int u = x[threadIdx.x];
    int e = (u >> 23) & 0xFF;
    unsigned long long m = __ballot(e >= 200);
    if (threadIdx.x == 0) flags[0] = (m != 0ULL) ? 1 : 0;
}

// ---------------------------------------------------------------------------
// weight repack: OIHW (+element offset) -> [tap][co(pad)][ci] bf16
// ---------------------------------------------------------------------------
__global__ void repack_off_k(const void* __restrict__ w, size_t w_off,
                             const int* __restrict__ flags, bf16* __restrict__ dst,
                             int Cout, int Cpad, int Cin, int total)
{
    const bool fw = flags[0] != 0;
    int i = blockIdx.x * 256 + threadIdx.x;
    if (i >= total) return;
    int ci = i % Cin; int r = i / Cin; int co = r % Cpad; int tap = r / Cpad;
    float v = 0.f;
    if (co < Cout) v = ldg_any(w, w_off + ((size_t)co * Cin + ci) * 9 + tap, fw);
    dst[i] = __float2bfloat16(v);
}

// ---------------------------------------------------------------------------
// Staging-chunk load: issue all 26 loads unconditionally (clamped address),
// raw bits into registers, validity carried in a bitmask. No data-dependent
// ops here so all loads stay in flight until the next LDS-write phase.
// ---------------------------------------------------------------------------
template<bool FIN>
__device__ __forceinline__ void load_chunk(const void* __restrict__ in, size_t cbase,
                                           int y0, int x0, int H, int W, int s_p0,
                                           unsigned (&pre)[26], unsigned& vmask)
{
    int rr = 0, cc2 = s_p0;
    unsigned m = 0;
#pragma unroll
    for (int i = 0; i < 26; ++i) {
        int pos = s_p0 + 8 * i;
        if (pos < 204) {
            int gy = y0 + rr - 1, gx = x0 + cc2 - 1;
            bool ok = ((unsigned)gy < (unsigned)H) && ((unsigned)gx < (unsigned)W);
            size_t off = ok ? cbase + (size_t)gy * W + gx : cbase;
            if (FIN) pre[i] = ((const unsigned short*)in)[off];
            else     pre[i] = ((const unsigned int*)in)[off];
            if (ok) m |= (1u << i);
        }
        cc2 += 8;
        if (cc2 >= 34) { cc2 -= 34; ++rr; }
    }
    vmask = m;
}

// ---------------------------------------------------------------------------
// MFMA implicit-GEMM 3x3 SAME conv, software-pipelined staging.
// Block tile: 128 co x (4 rows x 32 cols). 4 waves; wave wv owns row wv:
// 8 m-frags (16 co) x 2 n-frags (col halves). K loop: Cin chunks of 32,
// 9 taps per chunk. Staging for chunk k+1 is issued into registers before
// the MFMA phase of chunk k (latency hidden under MFMA issue).
// Optional fused input GroupNorm+ReLU applied at LDS-write time.
// ---------------------------------------------------------------------------
__global__ __launch_bounds__(256, 2) void conv3x3_mfma_k(
    const void* __restrict__ in, int inm,
    const bf16* __restrict__ wrep,
    const float* __restrict__ gstat, const void* __restrict__ gamma,
    const void* __restrict__ beta, size_t gb_off, int cpg, int Gn, float inv_pg,
    const void* __restrict__ bias, const void* __restrict__ scale, int sidx,
    void* __restrict__ out, int outm, size_t out_off,
    const int* __restrict__ flags,
    int Cin, int H, int W, int Cout, int Cpad, int co_blocks)
{
    const bool fin  = bfmode(inm, flags);
    const bool fw   = flags[0] != 0;
    const bool fout = bfmode(outm, flags);
    const int HW = H * W;

    const int t    = threadIdx.x;
    const int lane = t & 63;
    const int wv   = t >> 6;
    const int c    = lane & 15;
    const int quad = lane >> 4;
    const int x0   = blockIdx.x * 32;
    const int y0   = blockIdx.y * 4;
    const int n    = blockIdx.z / co_blocks;
    const int cb   = blockIdx.z % co_blocks;

    __shared__ __align__(16) bf16 s_b[204 * 40];   // [pos=rr*34+cc][ci swizzled]
    __shared__ float s_scale[256], s_shift[256];

    // per-input-channel norm precompute
    if (gstat) {
        for (int ch = t; ch < Cin; ch += 256) {
            int gl = n * Gn + ch / cpg;
            float mu  = gstat[2 * gl] * inv_pg;
            float var = fmaxf(gstat[2 * gl + 1] * inv_pg - mu * mu, 0.f);
            float iv  = rsqrtf(var + 1e-5f);
            float ga  = ldg_any(gamma, gb_off + ch, fw);
            float be  = ldg_any(beta,  gb_off + ch, fw);
            s_scale[ch] = iv * ga;
            s_shift[ch] = be - mu * iv * ga;
        }
    }
    const bool donorm = (gstat != nullptr);

    v4f acc[8][2];
#pragma unroll
    for (int i = 0; i < 8; ++i)
#pragma unroll
        for (int j = 0; j < 2; ++j) acc[i][j] = v4f{0.f, 0.f, 0.f, 0.f};

    const size_t inbase = (size_t)n * Cin * HW;
    // A-fragment per-lane base: co = cb*128 + mf*16 + c, k-octet = quad
    const size_t a_base = ((size_t)cb * 128 + c) * Cin + quad * 8;

    const int s_ci = t >> 3;      // staging: this thread's channel within chunk
    const int s_p0 = t & 7;       // staging: starting pos

    unsigned pre[26];
    unsigned vmask = 0;
    // prologue: issue chunk-0 loads
    if (fin) load_chunk<true >(in, inbase + (size_t)s_ci * HW, y0, x0, H, W, s_p0, pre, vmask);
    else     load_chunk<false>(in, inbase + (size_t)s_ci * HW, y0, x0, H, W, s_p0, pre, vmask);

    for (int ci0 = 0; ci0 < Cin; ci0 += 32) {
        __syncthreads();   // prior MFMA done with LDS; also publishes s_scale
        {
            float sc = 1.f, sh = 0.f;
            if (donorm) { sc = s_scale[ci0 + s_ci]; sh = s_shift[ci0 + s_ci]; }
#pragma unroll
            for (int i = 0; i < 26; ++i) {
                int pos = s_p0 + 8 * i;
                if (pos < 204) {
                    float v = fin ? __uint_as_float(pre[i] << 16)
                                  : __uint_as_float(pre[i]);
                    if (donorm) v = fmaxf(fmaf(v, sc, sh), 0.f);
                    v = ((vmask >> i) & 1u) ? v : 0.f;
                    int slot = (((s_ci >> 3) + pos) & 3) * 8 + (s_ci & 7);
                    s_b[pos * 40 + slot] = __float2bfloat16(v);
                }
            }
        }
        __syncthreads();

        // issue next chunk's loads; latency hides under the MFMA phase below
        if (ci0 + 32 < Cin) {
            size_t cb2 = inbase + (size_t)(ci0 + 32 + s_ci) * HW;
            if (fin) load_chunk<true >(in, cb2, y0, x0, H, W, s_p0, pre, vmask);
            else     load_chunk<false>(in, cb2, y0, x0, H, W, s_p0, pre, vmask);
        }

#pragma unroll
        for (int tap = 0; tap < 9; ++tap) {
            const int ky = tap / 3, kx = tap - ky * 3;
            v8s bfr[2];
#pragma unroll
            for (int nf = 0; nf < 2; ++nf) {
                int pos = (wv + ky) * 34 + c + nf * 16 + kx;
                bfr[nf] = *(const v8s*)&s_b[pos * 40 + (((quad + pos) & 3) * 8)];
            }
            const bf16* wt = wrep + a_base + ci0 + ((size_t)tap * Cpad) * Cin;
#pragma unroll
            for (int mf = 0; mf < 8; ++mf) {
                v8s af = *(const v8s*)(wt + (size_t)mf * 16 * Cin);
#pragma unroll
                for (int nf = 0; nf < 2; ++nf)
                    acc[mf][nf] = __builtin_amdgcn_mfma_f32_16x16x32_bf16(
                        af, bfr[nf], acc[mf][nf], 0, 0, 0);
            }
        }
    }

    // epilogue: C/D layout col=lane&15, row=quad*4+reg
    const float al = scale ? ldg_any(scale, sidx, fw) : 1.f;
    const int y = y0 + wv;
    if (y < H) {
#pragma unroll
        for (int mf = 0; mf < 8; ++mf) {
            int cobase = cb * 128 + mf * 16 + quad * 4;
#pragma unroll
            for (int reg = 0; reg < 4; ++reg) {
                int co = cobase + reg;
                if (co >= Cout) continue;
                float bv = bias ? ldg_any(bias, co, fw) : 0.f;
                size_t obase = out_off + ((size_t)n * Cout + co) * HW;
#pragma unroll
                for (int nf = 0; nf < 2; ++nf) {
                    int x = x0 + nf * 16 + c;
                    if (x < W)
                        stg_any(out, obase + (size_t)y * W + x,
                                fmaf(al, acc[mf][nf][reg], bv), fout);
                }
            }
        }
    }
}

// ---------------------------------------------------------------------------
// GroupNorm stats (vectorized bf16x8), atomic fp32 partials per group.
// ---------------------------------------------------------------------------
__global__ __launch_bounds__(256) void gn_stats_v(const bf16* __restrict__ x,
                                                  float* __restrict__ stats, int per_group)
{
    const int g = blockIdx.x;
    const uint4* xp = (const uint4*)(x + (size_t)g * per_group);
    const int nvec = per_group >> 3;
    float s = 0.f, ss = 0.f;
    const int stride = 256 * gridDim.y;
    for (int i = blockIdx.y * 256 + threadIdx.x; i < nvec; i += stride) {
        uint4 u = xp[i];
        float f0,f1,f2,f3,f4,f5,f6,f7;
        b2f2(u.x, f0, f1); b2f2(u.y, f2, f3); b2f2(u.z, f4, f5); b2f2(u.w, f6, f7);
        s += ((f0+f1)+(f2+f3)) + ((f4+f5)+(f6+f7));
        ss = fmaf(f0,f0,ss); ss = fmaf(f1,f1,ss); ss = fmaf(f2,f2,ss); ss = fmaf(f3,f3,ss);
        ss = fmaf(f4,f4,ss); ss = fmaf(f5,f5,ss); ss = fmaf(f6,f6,ss); ss = fmaf(f7,f7,ss);
    }
#pragma unroll
    for (int off = 32; off > 0; off >>= 1) {
        s  += __shfl_down(s,  off, 64);
        ss += __shfl_down(ss, off, 64);
    }
    __shared__ float sh[8];
    const int wv = threadIdx.x >> 6;
    if ((threadIdx.x & 63) == 0) { sh[wv * 2] = s; sh[wv * 2 + 1] = ss; }
    __syncthreads();
    if (threadIdx.x == 0) {
        s  = sh[0] + sh[2] + sh[4] + sh[6];
        ss = sh[1] + sh[3] + sh[5] + sh[7];
        atomicAdd(&stats[2 * g],     s);
        atomicAdd(&stats[2 * g + 1], ss);
    }
}

// GroupNorm apply + relu (vectorized; requires HW%8==0 at call sites)
__global__ void gn_apply_v(bf16* __restrict__ x, const float* __restrict__ stats,
                           const void* __restrict__ gamma, const void* __restrict__ beta,
                           size_t gb_off, const int* __restrict__ flags,
                           int HW, int C, int per_group, float inv_len, long nvec)
{
    const bool fw = flags[0] != 0;
    long v = (long)blockIdx.x * blockDim.x + threadIdx.x;
    if (v >= nvec) return;
    long i0 = v * 8;
    int gl = (int)(i0 / per_group);
    float mu  = stats[2 * gl] * inv_len;
    float var = fmaxf(stats[2 * gl + 1] * inv_len - mu * mu, 0.f);
    float iv  = rsqrtf(var + 1e-5f);
    int cc = (int)((i0 / HW) % C);
    float ga = ldg_any(gamma, gb_off + cc, fw);
    float be = ldg_any(beta,  gb_off + cc, fw);
    float sc = iv * ga, sf = be - mu * iv * ga;
    uint4 u = *(const uint4*)(x + i0);
    float f[8];
    b2f2(u.x, f[0], f[1]); b2f2(u.y, f[2], f[3]);
    b2f2(u.z, f[4], f[5]); b2f2(u.w, f[6], f[7]);
#pragma unroll
    for (int j = 0; j < 8; ++j) f[j] = fmaxf(fmaf(f[j], sc, sf), 0.f);
    uint4 o;
    o.x = f2b(f[0]) | ((unsigned)f2b(f[1]) << 16);
    o.y = f2b(f[2]) | ((unsigned)f2b(f[3]) << 16);
    o.z = f2b(f[4]) | ((unsigned)f2b(f[5]) << 16);
    o.w = f2b(f[6]) | ((unsigned)f2b(f[7]) << 16);
    *(uint4*)(x + i0) = o;
}

// ---------------------------------------------------------------------------
__global__ void extract_params_k(const void* __restrict__ pred3, const int* __restrict__ flags,
                                 float* __restrict__ prm, int HW)
{
    const bool bf = flags[0] != 0;
    int tid = blockIdx.x * blockDim.x + threadIdx.x;
    if (tid >= 200 * 169) return;
    int p = tid / 169, c = tid - p * 169;
    int b = p / 100, i = p - b * 100;
    prm[tid] = ldg_any(pred3, ((size_t)b * 254 + 85 + c) * HW + i, bf);
}

__global__ void upsample_add_k(const bf16* __restrict__ src, bf16* __restrict__ dst,
                               int h, int w, int OH, int OW, long total)
{
    long i = (long)blockIdx.x * blockDim.x + threadIdx.x;
    if (i >= total) return;
    int ox = (int)(i % OW);
    long r = i / OW;
    int oy = (int)(r % OH);
    int nc = (int)(r / OH);
    float sy = oy * ((h - 1.f) / (OH - 1.f));
    float sx = ox * ((w - 1.f) / (OW - 1.f));
    int y0 = (int)sy; int y1 = min(y0 + 1, h - 1); float wy = sy - y0;
    int x0 = (int)sx; int x1 = min(x0 + 1, w - 1); float wx = sx - x0;
    const bf16* sp = src + (size_t)nc * h * w;
    float t0 = cvt(sp[y0 * w + x0]) * (1.f - wy) + cvt(sp[y1 * w + x0]) * wy;
    float t1 = cvt(sp[y0 * w + x1]) * (1.f - wy) + cvt(sp[y1 * w + x1]) * wy;
    float v = cvt(dst[i]) + t0 * (1.f - wx) + t1 * wx;
    dst[i] = __float2bfloat16(v);
}

__global__ void resize_out_k(const float* __restrict__ src, void* __restrict__ dst,
                             size_t dst_off, const int* __restrict__ flags,
                             int h, int w, int OH, int OW, long total)
{
    const bool bf = flags[0] != 0;
    long i = (long)blockIdx.x * blockDim.x + threadIdx.x;
    if (i >= total) return;
    int ox = (int)(i % OW);
    long r = i / OW;
    int oy = (int)(r % OH);
    int nc = (int)(r / OH);
    float sy = oy * ((h - 1.f) / (OH - 1.f));
    float sx = ox * ((w - 1.f) / (OW - 1.f));
    int y0 = (int)sy; int y1 = min(y0 + 1, h - 1); float wy = sy - y0;
    int x0 = (int)sx; int x1 = min(x0 + 1, w - 1); float wx = sx - x0;
    const float* sp = src + (size_t)nc * h * w;
    float t0 = sp[y0 * w + x0] * (1.f - wy) + sp[y1 * w + x0] * wy;
    float t1 = sp[y0 * w + x1] * (1.f - wy) + sp[y1 * w + x1] * wy;
    stg_any(dst, dst_off + (size_t)i, t0 * (1.f - wx) + t1 * wx, bf);
}

__global__ void cast_out_k(const bf16* __restrict__ src, void* __restrict__ dst,
                           size_t dst_off, const int* __restrict__ flags, long n)
{
    const bool bf = flags[0] != 0;
    long i = (long)blockIdx.x * blockDim.x + threadIdx.x;
    if (i < n) stg_any(dst, dst_off + (size_t)i, cvt(src[i]), bf);
}

__global__ void conv1x1_k(const bf16* __restrict__ in, const void* __restrict__ w,
                          const int* __restrict__ flags,
                          bf16* __restrict__ out, int N, int Cin, int Cout, int HW)
{
    const bool fw = flags[0] != 0;
    long total = (long)N * Cout * HW;
    long idx = (long)blockIdx.x * blockDim.x + threadIdx.x;
    if (idx >= total) return;
    int p  = (int)(idx % HW);
    int co = (int)((idx / HW) % Cout);
    int n  = (int)(idx / ((long)HW * Cout));
    float s = 0.f;
    const bf16* ip = in + (size_t)n * Cin * HW + p;
    for (int ci = 0; ci < Cin; ++ci)
        s = fmaf(ldg_any(w, (size_t)co * Cin + ci, fw), cvt(ip[(size_t)ci * HW]), s);
    out[idx] = __float2bfloat16(s);
}

__global__ __launch_bounds__(256) void dyn_conv_k(const bf16* __restrict__ mf,
                                                  const float* __restrict__ prm,
                                                  float* __restrict__ out, int H, int W)
{
    const int inst = blockIdx.y;
    __shared__ float p[169];
    if (threadIdx.x < 169) p[threadIdx.x] = prm[inst * 169 + threadIdx.x];
    __syncthreads();
    const int HW = H * W;
    const int pix = blockIdx.x * 256 + threadIdx.x;
    if (pix >= HW) return;
    const int b = inst / 100;
    float xin[10];
#pragma unroll
    for (int c = 0; c < 8; ++c) xin[c] = cvt(mf[((size_t)(b * 8 + c)) * HW + pix]);
    int yy = pix / W, xx = pix - yy * W;
    xin[8] = -1.f + 2.f * xx / (W - 1);
    xin[9] = -1.f + 2.f * yy / (H - 1);
    float h1[8];
#pragma unroll
    for (int o = 0; o < 8; ++o) {
        float s = p[152 + o];
#pragma unroll
        for (int c = 0; c < 10; ++c) s = fmaf(p[o * 10 + c], xin[c], s);
        h1[o] = fmaxf(s, 0.f);
    }
    float h2[8];
#pragma unroll
    for (int o = 0; o < 8; ++o) {
        float s = p[160 + o];
#pragma unroll
        for (int c = 0; c < 8; ++c) s = fmaf(p[80 + o * 8 + c], h1[c], s);
        h2[o] = fmaxf(s, 0.f);
    }
    float s = p[168];
#pragma unroll
    for (int c = 0; c < 8; ++c) s = fmaf(p[144 + c], h2[c], s);
    out[(size_t)inst * HW + pix] = s;
}

// ---------------------------------------------------------------------------
// host helpers
// ---------------------------------------------------------------------------
struct Norm { const float* st; const void* g; const void* b; size_t off; int cpg; int Gn; float inv; };

static inline void mconv(const void* in, int inm, const bf16* wrep, const Norm* nm,
                         const void* bias, const void* scale, int sidx,
                         void* out, int outm, size_t out_off, const int* flags,
                         int N, int Cin, int H, int W, int Cout, hipStream_t s)
{
    int cob = (Cout + 127) / 128, Cpad = cob * 128;
    dim3 g((W + 31) / 32, (H + 3) / 4, N * cob);
    conv3x3_mfma_k<<<g, 256, 0, s>>>(
        in, inm, wrep,
        nm ? nm->st : nullptr, nm ? nm->g : nullptr, nm ? nm->b : nullptr,
        nm ? nm->off : 0, nm ? nm->cpg : 1, nm ? nm->Gn : 1, nm ? nm->inv : 1.f,
        bias, scale, sidx, out, outm, out_off, flags, Cin, H, W, Cout, Cpad, cob);
}

static inline void run_stats(const bf16* x, float* st, int ngroups, int per_group, hipStream_t s)
{
    int chunks = per_group / 8192; if (chunks < 1) chunks = 1; if (chunks > 64) chunks = 64;
    gn_stats_v<<<dim3(ngroups, chunks), 256, 0, s>>>(x, st, per_group);
}

static inline void run_apply(bf16* x, const float* st, const void* g, const void* b,
                             size_t off, const int* flags, int N, int C, int Gn, int HW,
                             hipStream_t s)
{
    int per_group = (C / Gn) * HW;
    long nvec = ((long)N * C * HW) >> 3;
    gn_apply_v<<<(int)((nvec + 255) / 256), 256, 0, s>>>(
        x, st, g, b, off, flags, HW, C, per_group, 1.f / per_group, nvec);
}

extern "C" void kernel_launch(void* const* d_in, const int* in_sizes, int n_in,
                              void* d_out, int out_size, void* d_ws, size_t ws_size,
                              hipStream_t stream)
{
    const void* f[5] = {d_in[0], d_in[1], d_in[2], d_in[3], d_in[4]};
    static const int Hs[5] = {96, 48, 24, 12, 6};
    static const int Wd[5] = {160, 80, 40, 20, 10};
    const void* head_w     = d_in[5];
    const void* head_gn_g  = d_in[6];
    const void* head_gn_b  = d_in[7];
    const void* head_out_w = d_in[8];
    const void* head_out_b = d_in[9];
    const void* scales     = d_in[10];
    const void* ref_w      = d_in[11];
    const void* ref_gn_g   = d_in[12];
    const void* ref_gn_b   = d_in[13];
    const void* tow_w      = d_in[14];
    const void* tow_gn_g   = d_in[15];
    const void* tow_gn_b   = d_in[16];
    const void* out_w      = d_in[17];
    const void* out_gn_g   = d_in[18];
    const void* out_gn_b   = d_in[19];

    size_t po[5]; size_t off = 0;
    for (int l = 0; l < 5; ++l) { po[l] = off; off += (size_t)2 * 254 * Hs[l] * Wd[l]; }
    size_t mf_off = off; off += 245760;
    size_t ml_off = off;

    // ---- workspace (~38 MB) ----
    bf16*  bufA  = (bf16*)d_ws;                 // 7,864,320 bf16
    bf16*  bufB  = bufA + 7864320;              // 7,864,320 bf16
    bf16*  mfeat = bufB + 7864320;              // 245,760 bf16
    float* prm   = (float*)(mfeat + 245760);    // 33,800 f32
    float* stats = prm + 33800;                 // 4,096 f32
    int*   flags = (int*)(stats + 4096);        // 16 int
    bf16*  wrep  = (bf16*)(flags + 16);         // 2,949,120 bf16
    float* dyn   = (float*)bufA;                // aliases bufA after last read

    bf16* wrepH  = wrep;                        // 4 x 589824 (head layers)
    bf16* wrepHO = wrep + 4 * 589824;           // 589824 (head_out, Cpad 256)
    bf16* wrepR  = wrep;                        // mask phase reuses region
    bf16* wrepT  = wrep + 3 * 294912;

    hipMemsetAsync(stats, 0, 4096 * sizeof(float), stream);
    detect_k<<<1, 64, 0, stream>>>((const unsigned int*)d_in[0], flags);

    float* sp = stats;

    // repack head weights (layered, reused across 5 levels)
    {
        for (int l = 0; l < 4; ++l) {
            int total = 9 * 256 * 256;
            repack_off_k<<<(total + 255) / 256, 256, 0, stream>>>(
                head_w, (size_t)l * 589824, flags, wrepH + (size_t)l * 589824, 256, 256, 256, total);
        }
        int total = 9 * 256 * 256;
        repack_off_k<<<(total + 255) / 256, 256, 0, stream>>>(
            head_out_w, 0, flags, wrepHO, 254, 256, 256, total);
    }

    // ---------------- head branches ----------------
    for (int lvl = 0; lvl < 5; ++lvl) {
        int H = Hs[lvl], W = Wd[lvl], HW = H * W;
        float inv_pg = 1.f / (8 * HW);
        mconv(f[lvl], 2, wrepH, nullptr, nullptr, nullptr, 0, bufA, 1, 0,
              flags, 2, 256, H, W, 256, stream);
        float* s_prev = sp; sp += 128;
        run_stats(bufA, s_prev, 64, 8 * HW, stream);
        bf16* a = bufA; bf16* bb = bufB;
        for (int l = 1; l < 4; ++l) {
            Norm nm{s_prev, head_gn_g, head_gn_b, (size_t)(l - 1) * 256, 8, 32, inv_pg};
            mconv(a, 1, wrepH + (size_t)l * 589824, &nm, nullptr, nullptr, 0,
                  bb, 1, 0, flags, 2, 256, H, W, 256, stream);
            s_prev = sp; sp += 128;
            run_stats(bb, s_prev, 64, 8 * HW, stream);
            bf16* tmp = a; a = bb; bb = tmp;
        }
        Norm nm{s_prev, head_gn_g, head_gn_b, (size_t)3 * 256, 8, 32, inv_pg};
        mconv(a, 1, wrepHO, &nm, head_out_b, scales, lvl, d_out, 2, po[lvl],
              flags, 2, 256, H, W, 254, stream);
        if (lvl == 0)
            extract_params_k<<<(200 * 169 + 255) / 256, 256, 0, stream>>>(d_out, flags, prm, HW);
    }

    // repack mask weights (head convs all enqueued; stream order protects region)
    {
        for (int i = 0; i < 3; ++i) {
            int total = 9 * 128 * 256;
            repack_off_k<<<(total + 255) / 256, 256, 0, stream>>>(
                ref_w, (size_t)i * 294912, flags, wrepR + (size_t)i * 294912, 128, 128, 256, total);
        }
        for (int l = 0; l < 4; ++l) {
            int total = 9 * 128 * 128;
            repack_off_k<<<(total + 255) / 256, 256, 0, stream>>>(
                tow_w, (size_t)l * 147456, flags, wrepT + (size_t)l * 147456, 128, 128, 128, total);
        }
    }

    // ---------------- mask branch ----------------
    {
        int H = 96, W = 160, HW = H * W;
        // refine 0
        mconv(f[0], 2, wrepR, nullptr, nullptr, nullptr, 0, bufA, 1, 0,
              flags, 2, 256, H, W, 128, stream);
        float* s0 = sp; sp += 4;
        run_stats(bufA, s0, 2, 128 * HW, stream);
        run_apply(bufA, s0, ref_gn_g, ref_gn_b, 0, flags, 2, 128, 1, HW, stream);
        // refines 1,2 + upsample-add
        for (int i = 1; i < 3; ++i) {
            int h = Hs[i], w2 = Wd[i], hw = h * w2;
            mconv(f[i], 2, wrepR + (size_t)i * 294912, nullptr, nullptr, nullptr, 0,
                  bufB, 1, 0, flags, 2, 256, h, w2, 128, stream);
            float* si = sp; sp += 4;
            run_stats(bufB, si, 2, 128 * hw, stream);
            run_apply(bufB, si, ref_gn_g, ref_gn_b, (size_t)i * 128, flags, 2, 128, 1, hw, stream);
            long tot = (long)2 * 128 * HW;
            upsample_add_k<<<(int)((tot + 255) / 256), 256, 0, stream>>>(bufB, bufA, h, w2, H, W, tot);
        }
        // tower (normalized input in bufA)
        float inv_pg = 1.f / (128 * HW);
        mconv(bufA, 1, wrepT, nullptr, nullptr, nullptr, 0, bufB, 1, 0,
              flags, 2, 128, H, W, 128, stream);
        float* sT = sp; sp += 4;
        run_stats(bufB, sT, 2, 128 * HW, stream);
        bf16* a = bufB; bf16* bb = bufA;
        for (int l = 1; l < 4; ++l) {
            Norm nm{sT, tow_gn_g, tow_gn_b, (size_t)(l - 1) * 128, 128, 1, inv_pg};
            mconv(a, 1, wrepT + (size_t)l * 147456, &nm, nullptr, nullptr, 0,
                  bb, 1, 0, flags, 2, 128, H, W, 128, stream);
            sT = sp; sp += 4;
            run_stats(bb, sT, 2, 128 * HW, stream);
            bf16* tmp = a; a = bb; bb = tmp;
        }
        // tower output raw in a (= bufA after 3 swaps), stats sT for layer 3
        run_apply(a, sT, tow_gn_g, tow_gn_b, (size_t)3 * 128, flags, 2, 128, 1, HW, stream);
        conv1x1_k<<<(2 * 8 * HW + 255) / 256, 256, 0, stream>>>(a, out_w, flags, mfeat, 2, 128, 8, HW);
        float* sM = sp; sp += 4;
        run_stats(mfeat, sM, 2, 8 * HW, stream);
        run_apply(mfeat, sM, out_gn_g, out_gn_b, 0, flags, 2, 8, 1, HW, stream);
        cast_out_k<<<(2 * 8 * HW + 255) / 256, 256, 0, stream>>>(mfeat, d_out, mf_off, flags, (long)2 * 8 * HW);
        dyn_conv_k<<<dim3((HW + 255) / 256, 200), 256, 0, stream>>>(mfeat, prm, dyn, H, W);
        long nt = (long)200 * 192 * 320;
        resize_out_k<<<(int)((nt + 255) / 256), 256, 0, stream>>>(dyn, d_out, ml_off, flags, 96, 160, 192, 320, nt);
    }
}

// Round 2
// 5749.120 us; speedup vs baseline: 1.0512x; 1.0512x over previous
//
#include <hip/hip_runtime.h>
#include <hip/hip_bf16.h>

typedef __hip_bfloat16 bf16;
typedef short v8s __attribute__((ext_vector_type(8)));
typedef float v4f __attribute__((ext_vector_type(4)));

__device__ __forceinline__ float cvt(bf16 v) { return __bfloat162float(v); }

__device__ __forceinline__ float ldg_any(const void* p, size_t i, bool bf) {
    return bf ? cvt(((const bf16*)p)[i]) : ((const float*)p)[i];
}
__device__ __forceinline__ void stg_any(void* p, size_t i, float v, bool bf) {
    if (bf) ((bf16*)p)[i] = __float2bfloat16(v);
    else    ((float*)p)[i] = v;
}
__device__ __forceinline__ bool bfmode(int mode, const int* flags) {
    return mode == 2 ? (flags[0] != 0) : (mode != 0);
}
__device__ __forceinline__ unsigned short f2b(float f) {
    bf16 h = __float2bfloat16(f); return *(unsigned short*)&h;
}
__device__ __forceinline__ bf16 bits2bf(unsigned short u) {
    bf16 h; *(unsigned short*)&h = u; return h;
}
__device__ __forceinline__ void b2f2(unsigned u, float& a, float& b) {
    a = __uint_as_float(u << 16);
    b = __uint_as_float(u & 0xffff0000u);
}

union U16x8 { uint4 u; unsigned short s[8]; };

// ---------------------------------------------------------------------------
// dtype probe on f3 (N(0,1) data): fp32 never has exponent >= 200.
// ---------------------------------------------------------------------------
__global__ void detect_k(const unsigned int* __restrict__ x, int* __restrict__ flags)
{
    unsigned int u = x[threadIdx.x];
    int e = (u >> 23) & 0xFF;
    unsigned long long m = __ballot(e >= 200);
    if (threadIdx.x == 0) flags[0] = (m != 0ULL) ? 1 : 0;
}

// ---------------------------------------------------------------------------
// weight repack: OIHW (+element offset) -> [tap][co(pad)][ci] bf16
// ---------------------------------------------------------------------------
__global__ void repack_off_k(const void* __restrict__ w, size_t w_off,
                             const int* __restrict__ flags, bf16* __restrict__ dst,
                             int Cout, int Cpad, int Cin, int total)
{
    const bool fw = flags[0] != 0;
    int i = blockIdx.x * 256 + threadIdx.x;
    if (i >= total) return;
    int ci = i % Cin; int r = i / Cin; int co = r % Cpad; int tap = r / Cpad;
    float v = 0.f;
    if (co < Cout) v = ldg_any(w, w_off + ((size_t)co * Cin + ci) * 9 + tap, fw);
    dst[i] = __float2bfloat16(v);
}

// ---------------------------------------------------------------------------
// pad: raw NCHW (fp32 or bf16) -> padded bf16 planes [NC][Hp][Wp], border zero.
// Padded row r maps to src row r-1; padded col pc maps to src col pc-8.
// ---------------------------------------------------------------------------
__global__ void pad_k(const void* __restrict__ src, const int* __restrict__ flags,
                      bf16* __restrict__ dst, int H, int W, int Wp, int Psz, long nvec)
{
    const bool fb = flags[0] != 0;
    long v = (long)blockIdx.x * 256 + threadIdx.x;
    if (v >= nvec) return;
    long i0 = v * 8;
    int plane = (int)(i0 / Psz);
    int rem = (int)(i0 - (long)plane * Psz);
    int r = rem / Wp, c0 = rem - r * Wp;
    const bool rowin = (r >= 1) && (r <= H);
    size_t sbase = (size_t)plane * H * W + (size_t)(r - 1) * W;
    U16x8 o;
#pragma unroll
    for (int e = 0; e < 8; ++e) {
        int pc = c0 + e;
        float val = 0.f;
        if (rowin && pc >= 8 && pc < 8 + W) val = ldg_any(src, sbase + (pc - 8), fb);
        o.s[e] = f2b(val);
    }
    *(uint4*)(dst + i0) = o.u;
}

// ---------------------------------------------------------------------------
// MFMA implicit-GEMM 3x3 SAME conv on PADDED bf16 input.
// Block tile: 128 co x (4 rows x 32 cols). 4 waves, wave wv owns row wv:
// 8 m-frags x 2 n-frags. K loop: Cin chunks of 32, 9 taps each.
// Staging: per chunk exactly 1152 coalesced uint4 (16B) loads from the padded
// planes (no bounds checks), transposed into LDS [pos][ci-swizzled] with b16
// writes. Double-buffered LDS; chunk k+1 loads issue before MFMA of chunk k.
// Optional fused GroupNorm+ReLU (stats of previous layer) at LDS-write time
// (borders re-zeroed by mask there). Optional epilogue alpha/bias.
// ---------------------------------------------------------------------------
__global__ __launch_bounds__(256, 2) void conv3x3_mfma_k(
    const bf16* __restrict__ in,
    const bf16* __restrict__ wrep,
    const float* __restrict__ gstat, const void* __restrict__ gamma,
    const void* __restrict__ beta, size_t gb_off, int cpg, int Gn, float inv_pg,
    const void* __restrict__ bias, const void* __restrict__ scale, int sidx,
    void* __restrict__ out, int outm, size_t out_off,
    long out_pst, int out_rst, int out_ro, int out_co,
    const int* __restrict__ flags,
    int Cin, int H, int W, int Wp, int Psz, int Cout, int Cpad, int co_blocks)
{
    const bool fw   = flags[0] != 0;
    const bool fout = bfmode(outm, flags);
    const int Hp = H + 2;

    const int t    = threadIdx.x;
    const int lane = t & 63;
    const int wv   = t >> 6;
    const int c    = lane & 15;
    const int quad = lane >> 4;
    const int x0   = blockIdx.x * 32;
    const int y0   = blockIdx.y * 4;
    const int n    = blockIdx.z / co_blocks;
    const int cb   = blockIdx.z % co_blocks;

    __shared__ __align__(16) bf16 s_b[2][204 * 40];   // [pos=row*34+cc][ci swizzled]
    __shared__ float s_scale[256], s_shift[256];

    const bool donorm = (gstat != nullptr);
    if (donorm) {
        for (int ch = t; ch < Cin; ch += 256) {
            int gl = n * Gn + ch / cpg;
            float mu  = gstat[2 * gl] * inv_pg;
            float var = fmaxf(gstat[2 * gl + 1] * inv_pg - mu * mu, 0.f);
            float iv  = rsqrtf(var + 1e-5f);
            float ga  = ldg_any(gamma, gb_off + ch, fw);
            float be  = ldg_any(beta,  gb_off + ch, fw);
            s_scale[ch] = iv * ga;
            s_shift[ch] = be - mu * iv * ga;
        }
    }

    v4f acc[8][2];
#pragma unroll
    for (int i = 0; i < 8; ++i)
#pragma unroll
        for (int j = 0; j < 2; ++j) acc[i][j] = v4f{0.f, 0.f, 0.f, 0.f};

    const bf16* inb = in + (size_t)n * Cin * Psz;
    const size_t a_base = ((size_t)cb * 128 + c) * Cin + (size_t)quad * 8;

    // staging map: flat f = t + 256*it (f < 1152): ci=f/36, row=(f%36)/6, cbk=f%6
    int s_ci[5], s_row[5], s_cbk[5];
#pragma unroll
    for (int it = 0; it < 5; ++it) {
        int fidx = t + 256 * it;
        s_ci[it] = fidx / 36; int rem = fidx - s_ci[it] * 36;
        s_row[it] = rem / 6; s_cbk[it] = rem - s_row[it] * 6;
    }
    const bool has4 = (t < 128);   // wave-uniform (waves 0,1 true; 2,3 false)

    uint4 L[5];

    auto LOAD = [&](int ci0) {
#pragma unroll
        for (int it = 0; it < 5; ++it) {
            if (it == 4 && !has4) continue;
            int prow = y0 + s_row[it]; if (prow > Hp - 1) prow = Hp - 1;
            const bf16* p = inb + (size_t)(ci0 + s_ci[it]) * Psz
                                + (size_t)prow * Wp + x0 + s_cbk[it] * 8;
            L[it] = *(const uint4*)p;
        }
    };

    auto WRITE = [&](int buf, int ci0) {
#pragma unroll
        for (int it = 0; it < 5; ++it) {
            if (it == 4 && !has4) continue;
            const int ci = s_ci[it], row = s_row[it], cbk = s_cbk[it];
            float sc = 1.f, sh = 0.f;
            if (donorm) { sc = s_scale[ci0 + ci]; sh = s_shift[ci0 + ci]; }
            const int gy = y0 + row - 1;
            const bool rok = (unsigned)gy < (unsigned)H;
            U16x8 q; q.u = L[it];
#pragma unroll
            for (int e = 0; e < 8; ++e) {
                int cc = cbk * 8 + e - 7;
                if (cc < 0 || cc >= 34) continue;
                bf16 outv;
                if (donorm) {
                    int gx = x0 - 8 + cbk * 8 + e;
                    float v = __uint_as_float((unsigned)q.s[e] << 16);
                    v = fmaxf(fmaf(v, sc, sh), 0.f);
                    if (!(rok && (unsigned)gx < (unsigned)W)) v = 0.f;
                    outv = __float2bfloat16(v);
                } else {
                    outv = bits2bf(q.s[e]);
                }
                int pos = row * 34 + cc;
                int slot = (((ci >> 3) + pos) & 3) * 8 + (ci & 7);
                s_b[buf][pos * 40 + slot] = outv;
            }
        }
    };

    auto MFMA = [&](int buf, int ci0) {
#pragma unroll
        for (int tap = 0; tap < 9; ++tap) {
            const int ky = tap / 3, kx = tap - ky * 3;
            v8s bfr[2];
#pragma unroll
            for (int nf = 0; nf < 2; ++nf) {
                int pos = (wv + ky) * 34 + c + nf * 16 + kx;
                bfr[nf] = *(const v8s*)&s_b[buf][pos * 40 + (((quad + pos) & 3) * 8)];
            }
            const bf16* wt = wrep + a_base + ci0 + ((size_t)tap * Cpad) * Cin;
#pragma unroll
            for (int mf = 0; mf < 8; ++mf) {
                v8s af = *(const v8s*)(wt + (size_t)mf * 16 * Cin);
#pragma unroll
                for (int nf = 0; nf < 2; ++nf)
                    acc[mf][nf] = __builtin_amdgcn_mfma_f32_16x16x32_bf16(
                        af, bfr[nf], acc[mf][nf], 0, 0, 0);
            }
        }
    };

    LOAD(0);
    __syncthreads();           // publishes s_scale/s_shift too
    WRITE(0, 0);
    __syncthreads();
    for (int ci0 = 0; ci0 < Cin; ci0 += 32) {
        const int buf = (ci0 >> 5) & 1;
        const bool more = (ci0 + 32 < Cin);
        if (more) LOAD(ci0 + 32);          // latency hides under MFMA below
        MFMA(buf, ci0);
        if (more) WRITE(buf ^ 1, ci0 + 32);
        __syncthreads();
    }

    // epilogue: C/D layout col=lane&15, row=quad*4+reg
    const float al = scale ? ldg_any(scale, sidx, fw) : 1.f;
    const int y = y0 + wv;
    if (y < H) {
#pragma unroll
        for (int mf = 0; mf < 8; ++mf) {
            int cobase = cb * 128 + mf * 16 + quad * 4;
#pragma unroll
            for (int reg = 0; reg < 4; ++reg) {
                int co = cobase + reg;
                if (co >= Cout) continue;
                float bv = bias ? ldg_any(bias, co, fw) : 0.f;
                size_t obase = out_off + (size_t)((size_t)n * Cout + co) * out_pst
                             + (size_t)(y + out_ro) * out_rst + out_co;
#pragma unroll
                for (int nf = 0; nf < 2; ++nf) {
                    int x = x0 + nf * 16 + c;
                    if (x < W)
                        stg_any(out, obase + x, fmaf(al, acc[mf][nf][reg], bv), fout);
                }
            }
        }
    }
}

// ---------------------------------------------------------------------------
// GroupNorm stats (vectorized bf16x8), atomic fp32 partials per group.
// Works on padded buffers too: borders are zero so they add nothing; caller
// passes per_group in PADDED elements and uses the true count for 1/len.
// ---------------------------------------------------------------------------
__global__ __launch_bounds__(256) void gn_stats_v(const bf16* __restrict__ x,
                                                  float* __restrict__ stats, int per_group)
{
    const int g = blockIdx.x;
    const uint4* xp = (const uint4*)(x + (size_t)g * per_group);
    const int nvec = per_group >> 3;
    float s = 0.f, ss = 0.f;
    const int stride = 256 * gridDim.y;
    for (int i = blockIdx.y * 256 + threadIdx.x; i < nvec; i += stride) {
        uint4 u = xp[i];
        float f0,f1,f2,f3,f4,f5,f6,f7;
        b2f2(u.x, f0, f1); b2f2(u.y, f2, f3); b2f2(u.z, f4, f5); b2f2(u.w, f6, f7);
        s += ((f0+f1)+(f2+f3)) + ((f4+f5)+(f6+f7));
        ss = fmaf(f0,f0,ss); ss = fmaf(f1,f1,ss); ss = fmaf(f2,f2,ss); ss = fmaf(f3,f3,ss);
        ss = fmaf(f4,f4,ss); ss = fmaf(f5,f5,ss); ss = fmaf(f6,f6,ss); ss = fmaf(f7,f7,ss);
    }
#pragma unroll
    for (int off = 32; off > 0; off >>= 1) {
        s  += __shfl_down(s,  off, 64);
        ss += __shfl_down(ss, off, 64);
    }
    __shared__ float sh[8];
    const int wv = threadIdx.x >> 6;
    if ((threadIdx.x & 63) == 0) { sh[wv * 2] = s; sh[wv * 2 + 1] = ss; }
    __syncthreads();
    if (threadIdx.x == 0) {
        s  = sh[0] + sh[2] + sh[4] + sh[6];
        ss = sh[1] + sh[3] + sh[5] + sh[7];
        atomicAdd(&stats[2 * g],     s);
        atomicAdd(&stats[2 * g + 1], ss);
    }
}

// GroupNorm apply + relu, FLAT layout (mfeat), requires HW%8==0
__global__ void gn_apply_v(bf16* __restrict__ x, const float* __restrict__ stats,
                           const void* __restrict__ gamma, const void* __restrict__ beta,
                           size_t gb_off, const int* __restrict__ flags,
                           int HW, int C, int per_group, float inv_len, long nvec)
{
    const bool fw = flags[0] != 0;
    long v = (long)blockIdx.x * blockDim.x + threadIdx.x;
    if (v >= nvec) return;
    long i0 = v * 8;
    int gl = (int)(i0 / per_group);
    float mu  = stats[2 * gl] * inv_len;
    float var = fmaxf(stats[2 * gl + 1] * inv_len - mu * mu, 0.f);
    float iv  = rsqrtf(var + 1e-5f);
    int cc = (int)((i0 / HW) % C);
    float ga = ldg_any(gamma, gb_off + cc, fw);
    float be = ldg_any(beta,  gb_off + cc, fw);
    float sc = iv * ga, sf = be - mu * iv * ga;
    uint4 u = *(const uint4*)(x + i0);
    float f[8];
    b2f2(u.x, f[0], f[1]); b2f2(u.y, f[2], f[3]);
    b2f2(u.z, f[4], f[5]); b2f2(u.w, f[6], f[7]);
#pragma unroll
    for (int j = 0; j < 8; ++j) f[j] = fmaxf(fmaf(f[j], sc, sf), 0.f);
    uint4 o;
    o.x = f2b(f[0]) | ((unsigned)f2b(f[1]) << 16);
    o.y = f2b(f[2]) | ((unsigned)f2b(f[3]) << 16);
    o.z = f2b(f[4]) | ((unsigned)f2b(f[5]) << 16);
    o.w = f2b(f[6]) | ((unsigned)f2b(f[7]) << 16);
    *(uint4*)(x + i0) = o;
}

// GroupNorm apply + relu on PADDED layout, interior only (preserves zero
// borders). Requires W%8==0 (true for all call sites: W in {160,80,40}).
__global__ void gn_apply_pad(bf16* __restrict__ x, const float* __restrict__ stats,
                             const void* __restrict__ gamma, const void* __restrict__ beta,
                             size_t gb_off, const int* __restrict__ flags,
                             int C, int cpg, int Gn, int H, int W, int Wp, int Psz,
                             float inv_len, long total)
{
    const bool fw = flags[0] != 0;
    long v = (long)blockIdx.x * 256 + threadIdx.x;
    if (v >= total) return;
    int wv8 = W >> 3;
    int xb = (int)(v % wv8);
    long r2 = v / wv8;
    int y = (int)(r2 % H);
    int plane = (int)(r2 / H);
    int cc = plane % C, n = plane / C;
    int gl = n * Gn + cc / cpg;
    float mu  = stats[2 * gl] * inv_len;
    float var = fmaxf(stats[2 * gl + 1] * inv_len - mu * mu, 0.f);
    float iv  = rsqrtf(var + 1e-5f);
    float ga = ldg_any(gamma, gb_off + cc, fw);
    float be = ldg_any(beta,  gb_off + cc, fw);
    float sc = iv * ga, sf = be - mu * iv * ga;
    long base = (long)plane * Psz + (long)(y + 1) * Wp + 8 + (long)xb * 8;
    uint4 u = *(const uint4*)(x + base);
    float f[8];
    b2f2(u.x, f[0], f[1]); b2f2(u.y, f[2], f[3]);
    b2f2(u.z, f[4], f[5]); b2f2(u.w, f[6], f[7]);
#pragma unroll
    for (int j = 0; j < 8; ++j) f[j] = fmaxf(fmaf(f[j], sc, sf), 0.f);
    uint4 o;
    o.x = f2b(f[0]) | ((unsigned)f2b(f[1]) << 16);
    o.y = f2b(f[2]) | ((unsigned)f2b(f[3]) << 16);
    o.z = f2b(f[4]) | ((unsigned)f2b(f[5]) << 16);
    o.w = f2b(f[6]) | ((unsigned)f2b(f[7]) << 16);
    *(uint4*)(x + base) = o;
}

// ---------------------------------------------------------------------------
__global__ void extract_params_k(const void* __restrict__ pred3, const int* __restrict__ flags,
                                 float* __restrict__ prm, int HW)
{
    const bool bf = flags[0] != 0;
    int tid = blockIdx.x * blockDim.x + threadIdx.x;
    if (tid >= 200 * 169) return;
    int p = tid / 169, c = tid - p * 169;
    int b = p / 100, i = p - b * 100;
    prm[tid] = ldg_any(pred3, ((size_t)b * 254 + 85 + c) * HW + i, bf);
}

// bilinear upsample (align corners) padded src -> add into padded dst interior
__global__ void upsample_add_k(const bf16* __restrict__ src, bf16* __restrict__ dst,
                               int h, int w, int sWp, int sPsz,
                               int OH, int OW, int dWp, int dPsz, long total)
{
    long i = (long)blockIdx.x * blockDim.x + threadIdx.x;
    if (i >= total) return;
    int ox = (int)(i % OW);
    long r = i / OW;
    int oy = (int)(r % OH);
    int nc = (int)(r / OH);
    float sy = oy * ((h - 1.f) / (OH - 1.f));
    float sx = ox * ((w - 1.f) / (OW - 1.f));
    int y0 = (int)sy; int y1 = min(y0 + 1, h - 1); float wy = sy - y0;
    int x0 = (int)sx; int x1 = min(x0 + 1, w - 1); float wx = sx - x0;
    const bf16* sp = src + (size_t)nc * sPsz;
    float t0 = cvt(sp[(y0 + 1) * sWp + x0 + 8]) * (1.f - wy) + cvt(sp[(y1 + 1) * sWp + x0 + 8]) * wy;
    float t1 = cvt(sp[(y0 + 1) * sWp + x1 + 8]) * (1.f - wy) + cvt(sp[(y1 + 1) * sWp + x1 + 8]) * wy;
    bf16* dp = dst + (size_t)nc * dPsz + (size_t)(oy + 1) * dWp + ox + 8;
    *dp = __float2bfloat16(cvt(*dp) + t0 * (1.f - wx) + t1 * wx);
}

__global__ void resize_out_k(const float* __restrict__ src, void* __restrict__ dst,
                             size_t dst_off, const int* __restrict__ flags,
                             int h, int w, int OH, int OW, long total)
{
    const bool bf = flags[0] != 0;
    long i = (long)blockIdx.x * blockDim.x + threadIdx.x;
    if (i >= total) return;
    int ox = (int)(i % OW);
    long r = i / OW;
    int oy = (int)(r % OH);
    int nc = (int)(r / OH);
    float sy = oy * ((h - 1.f) / (OH - 1.f));
    float sx = ox * ((w - 1.f) / (OW - 1.f));
    int y0 = (int)sy; int y1 = min(y0 + 1, h - 1); float wy = sy - y0;
    int x0 = (int)sx; int x1 = min(x0 + 1, w - 1); float wx = sx - x0;
    const float* sp = src + (size_t)nc * h * w;
    float t0 = sp[y0 * w + x0] * (1.f - wy) + sp[y1 * w + x0] * wy;
    float t1 = sp[y0 * w + x1] * (1.f - wy) + sp[y1 * w + x1] * wy;
    stg_any(dst, dst_off + (size_t)i, t0 * (1.f - wx) + t1 * wx, bf);
}

__global__ void cast_out_k(const bf16* __restrict__ src, void* __restrict__ dst,
                           size_t dst_off, const int* __restrict__ flags, long n)
{
    const bool bf = flags[0] != 0;
    long i = (long)blockIdx.x * blockDim.x + threadIdx.x;
    if (i < n) stg_any(dst, dst_off + (size_t)i, cvt(src[i]), bf);
}

// 1x1 conv: padded bf16 input -> flat bf16 output
__global__ void conv1x1_k(const bf16* __restrict__ in, const void* __restrict__ w,
                          const int* __restrict__ flags, bf16* __restrict__ out,
                          int N, int Cin, int Cout, int H, int W, int Wp, int Psz)
{
    const bool fw = flags[0] != 0;
    const int HW = H * W;
    long total = (long)N * Cout * HW;
    long idx = (long)blockIdx.x * blockDim.x + threadIdx.x;
    if (idx >= total) return;
    int p  = (int)(idx % HW);
    int co = (int)((idx / HW) % Cout);
    int n  = (int)(idx / ((long)HW * Cout));
    int y = p / W, x2 = p - y * W;
    const bf16* ip = in + (size_t)n * Cin * Psz + (size_t)(y + 1) * Wp + 8 + x2;
    float s = 0.f;
    for (int ci = 0; ci < Cin; ++ci)
        s = fmaf(ldg_any(w, (size_t)co * Cin + ci, fw), cvt(ip[(size_t)ci * Psz]), s);
    out[idx] = __float2bfloat16(s);
}

__global__ __launch_bounds__(256) void dyn_conv_k(const bf16* __restrict__ mf,
                                                  const float* __restrict__ prm,
                                                  float* __restrict__ out, int H, int W)
{
    const int inst = blockIdx.y;
    __shared__ float p[169];
    if (threadIdx.x < 169) p[threadIdx.x] = prm[inst * 169 + threadIdx.x];
    __syncthreads();
    const int HW = H * W;
    const int pix = blockIdx.x * 256 + threadIdx.x;
    if (pix >= HW) return;
    const int b = inst / 100;
    float xin[10];
#pragma unroll
    for (int c = 0; c < 8; ++c) xin[c] = cvt(mf[((size_t)(b * 8 + c)) * HW + pix]);
    int yy = pix / W, xx = pix - yy * W;
    xin[8] = -1.f + 2.f * xx / (W - 1);
    xin[9] = -1.f + 2.f * yy / (H - 1);
    float h1[8];
#pragma unroll
    for (int o = 0; o < 8; ++o) {
        float s = p[152 + o];
#pragma unroll
        for (int c = 0; c < 10; ++c) s = fmaf(p[o * 10 + c], xin[c], s);
        h1[o] = fmaxf(s, 0.f);
    }
    float h2[8];
#pragma unroll
    for (int o = 0; o < 8; ++o) {
        float s = p[160 + o];
#pragma unroll
        for (int c = 0; c < 8; ++c) s = fmaf(p[80 + o * 8 + c], h1[c], s);
        h2[o] = fmaxf(s, 0.f);
    }
    float s = p[168];
#pragma unroll
    for (int c = 0; c < 8; ++c) s = fmaf(p[144 + c], h2[c], s);
    out[(size_t)inst * HW + pix] = s;
}

// ---------------------------------------------------------------------------
// host helpers
// ---------------------------------------------------------------------------
struct Norm { const float* st; const void* g; const void* b; size_t off; int cpg; int Gn; float inv; };
struct Geo  { int H, W, Wp, Psz; };

static inline void mconv(const bf16* in, const bf16* wrep, const Norm* nm,
                         const void* bias, const void* scale, int sidx,
                         void* out, int outm, size_t out_off,
                         long opst, int orst, int oro, int oco,
                         const int* flags, int N, int Cin, Geo g, int Cout, hipStream_t s)
{
    int cob = (Cout + 127) / 128, Cpad = cob * 128;
    dim3 gr((g.W + 31) / 32, (g.H + 3) / 4, N * cob);
    conv3x3_mfma_k<<<gr, 256, 0, s>>>(
        in, wrep,
        nm ? nm->st : nullptr, nm ? nm->g : nullptr, nm ? nm->b : nullptr,
        nm ? nm->off : 0, nm ? nm->cpg : 1, nm ? nm->Gn : 1, nm ? nm->inv : 1.f,
        bias, scale, sidx, out, outm, out_off, opst, orst, oro, oco,
        flags, Cin, g.H, g.W, g.Wp, g.Psz, Cout, Cpad, cob);
}

static inline void run_stats(const bf16* x, float* st, int ngroups, int per_group, hipStream_t s)
{
    int chunks = per_group / 8192; if (chunks < 1) chunks = 1; if (chunks > 64) chunks = 64;
    gn_stats_v<<<dim3(ngroups, chunks), 256, 0, s>>>(x, st, per_group);
}

static inline void run_pad(const void* src, const int* flags, bf16* dst,
                           int NC, Geo g, hipStream_t s)
{
    long nvec = ((long)NC * g.Psz) >> 3;
    pad_k<<<(int)((nvec + 255) / 256), 256, 0, s>>>(src, flags, dst, g.H, g.W, g.Wp, g.Psz, nvec);
}

static inline void run_apply_pad(bf16* x, const float* st, const void* gm, const void* bt,
                                 size_t off, const int* flags, int N, int C, int cpg, int Gn,
                                 Geo g, hipStream_t s)
{
    long total = (long)N * C * g.H * (g.W >> 3);
    gn_apply_pad<<<(int)((total + 255) / 256), 256, 0, s>>>(
        x, st, gm, bt, off, flags, C, cpg, Gn, g.H, g.W, g.Wp, g.Psz,
        1.f / ((float)cpg * g.H * g.W), total);
}

extern "C" void kernel_launch(void* const* d_in, const int* in_sizes, int n_in,
                              void* d_out, int out_size, void* d_ws, size_t ws_size,
                              hipStream_t stream)
{
    const void* f[5] = {d_in[0], d_in[1], d_in[2], d_in[3], d_in[4]};
    static const int Hs[5] = {96, 48, 24, 12, 6};
    static const int Wd[5] = {160, 80, 40, 20, 10};
    const void* head_w     = d_in[5];
    const void* head_gn_g  = d_in[6];
    const void* head_gn_b  = d_in[7];
    const void* head_out_w = d_in[8];
    const void* head_out_b = d_in[9];
    const void* scales     = d_in[10];
    const void* ref_w      = d_in[11];
    const void* ref_gn_g   = d_in[12];
    const void* ref_gn_b   = d_in[13];
    const void* tow_w      = d_in[14];
    const void* tow_gn_g   = d_in[15];
    const void* tow_gn_b   = d_in[16];
    const void* out_w      = d_in[17];
    const void* out_gn_g   = d_in[18];
    const void* out_gn_b   = d_in[19];

    // padded geometry per level: Wp = 32*(ceil(W/32)-1) + 48, Hp = H+2
    Geo G[5];
    for (int l = 0; l < 5; ++l) {
        int W = Wd[l], H = Hs[l];
        int Wp = ((W + 31) / 32 - 1) * 32 + 48;
        G[l] = Geo{H, W, Wp, (H + 2) * Wp};
    }
    // Psz: 17248, 5600, 2080, 672, 384

    size_t po[5]; size_t off = 0;
    for (int l = 0; l < 5; ++l) { po[l] = off; off += (size_t)2 * 254 * Hs[l] * Wd[l]; }
    size_t mf_off = off; off += 245760;
    size_t ml_off = off;

    // ---- workspace (~42 MB) ----
    const size_t ACAP = (size_t)2 * 256 * G[0].Psz;      // 8,830,976 elems
    bf16*  A     = (bf16*)d_ws;
    bf16*  B     = A + ACAP;
    bf16*  mfeat = B + ACAP;                              // 245,760 bf16
    float* prm   = (float*)(mfeat + 245760);              // 33,800 f32
    float* stats = prm + 33800;                           // 4,096 f32
    int*   flags = (int*)(stats + 4096);                  // 16 int
    bf16*  wrep  = (bf16*)(flags + 16);                   // 2,949,120 bf16
    float* dyn   = (float*)A;                             // aliases A after last read

    bf16* wrepH  = wrep;                        // 4 x 589824 (head layers)
    bf16* wrepHO = wrep + 4 * 589824;           // 589824 (head_out, Cpad 256)
    bf16* wrepR  = wrep;                        // mask phase reuses region
    bf16* wrepT  = wrep + 3 * 294912;

    hipMemsetAsync(stats, 0, 4096 * sizeof(float), stream);
    detect_k<<<1, 64, 0, stream>>>((const unsigned int*)d_in[0], flags);

    float* sp = stats;

    // repack head weights (layered, reused across 5 levels)
    for (int l = 0; l < 4; ++l) {
        int total = 9 * 256 * 256;
        repack_off_k<<<(total + 255) / 256, 256, 0, stream>>>(
            head_w, (size_t)l * 589824, flags, wrepH + (size_t)l * 589824, 256, 256, 256, total);
    }
    {
        int total = 9 * 256 * 256;
        repack_off_k<<<(total + 255) / 256, 256, 0, stream>>>(
            head_out_w, 0, flags, wrepHO, 254, 256, 256, total);
    }

    // ---------------- head branches ----------------
    for (int lvl = 0; lvl < 5; ++lvl) {
        Geo g = G[lvl];
        int H = g.H, W = g.W, HW = H * W;
        float inv_pg = 1.f / (8 * HW);
        hipMemsetAsync(A, 0, (size_t)2 * 256 * g.Psz * sizeof(bf16), stream);
        run_pad(f[lvl], flags, B, 2 * 256, g, stream);
        // conv1: B(raw padded) -> A
        mconv(B, wrepH, nullptr, nullptr, nullptr, 0, A, 1, 0, g.Psz, g.Wp, 1, 8,
              flags, 2, 256, g, 256, stream);
        float* s_prev = sp; sp += 128;
        run_stats(A, s_prev, 64, 8 * g.Psz, stream);
        bf16* a = A; bf16* bb = B;
        for (int l = 1; l < 4; ++l) {
            Norm nm{s_prev, head_gn_g, head_gn_b, (size_t)(l - 1) * 256, 8, 32, inv_pg};
            mconv(a, wrepH + (size_t)l * 589824, &nm, nullptr, nullptr, 0,
                  bb, 1, 0, g.Psz, g.Wp, 1, 8, flags, 2, 256, g, 256, stream);
            s_prev = sp; sp += 128;
            run_stats(bb, s_prev, 64, 8 * g.Psz, stream);
            bf16* tmp = a; a = bb; bb = tmp;
        }
        // conv5 (head out): a -> d_out (flat, runtime dtype)
        Norm nm{s_prev, head_gn_g, head_gn_b, (size_t)3 * 256, 8, 32, inv_pg};
        mconv(a, wrepHO, &nm, head_out_b, scales, lvl, d_out, 2, po[lvl],
              (long)HW, W, 0, 0, flags, 2, 256, g, 254, stream);
        if (lvl == 0)
            extract_params_k<<<(200 * 169 + 255) / 256, 256, 0, stream>>>(d_out, flags, prm, HW);
    }

    // repack mask weights (stream order protects the region)
    for (int i = 0; i < 3; ++i) {
        int total = 9 * 128 * 256;
        repack_off_k<<<(total + 255) / 256, 256, 0, stream>>>(
            ref_w, (size_t)i * 294912, flags, wrepR + (size_t)i * 294912, 128, 128, 256, total);
    }
    for (int l = 0; l < 4; ++l) {
        int total = 9 * 128 * 128;
        repack_off_k<<<(total + 255) / 256, 256, 0, stream>>>(
            tow_w, (size_t)l * 147456, flags, wrepT + (size_t)l * 147456, 128, 128, 128, total);
    }

    // ---------------- mask branch ----------------
    {
        Geo g0 = G[0];
        const int HW = 96 * 160;
        const size_t B2 = (size_t)2 * 256 * G[1].Psz;   // refine1/2 output region in B

        // refine 0
        hipMemsetAsync(A, 0, (size_t)2 * 128 * g0.Psz * sizeof(bf16), stream);
        run_pad(f[0], flags, B, 2 * 256, g0, stream);
        mconv(B, wrepR, nullptr, nullptr, nullptr, 0, A, 1, 0, g0.Psz, g0.Wp, 1, 8,
              flags, 2, 256, g0, 128, stream);
        float* s0 = sp; sp += 4;
        run_stats(A, s0, 2, 128 * g0.Psz, stream);
        run_apply_pad(A, s0, ref_gn_g, ref_gn_b, 0, flags, 2, 128, 128, 1, g0, stream);

        // refines 1,2 + upsample-add into A
        for (int i = 1; i < 3; ++i) {
            Geo gi = G[i];
            hipMemsetAsync(B + B2, 0, (size_t)2 * 128 * gi.Psz * sizeof(bf16), stream);
            run_pad(f[i], flags, B, 2 * 256, gi, stream);
            mconv(B, wrepR + (size_t)i * 294912, nullptr, nullptr, nullptr, 0,
                  B, 1, B2, gi.Psz, gi.Wp, 1, 8, flags, 2, 256, gi, 128, stream);
            float* si = sp; sp += 4;
            run_stats(B + B2, si, 2, 128 * gi.Psz, stream);
            run_apply_pad(B + B2, si, ref_gn_g, ref_gn_b, (size_t)i * 128, flags,
                          2, 128, 128, 1, gi, stream);
            long tot = (long)2 * 128 * HW;
            upsample_add_k<<<(int)((tot + 255) / 256), 256, 0, stream>>>(
                B + B2, A, gi.H, gi.W, gi.Wp, gi.Psz, 96, 160, g0.Wp, g0.Psz, tot);
        }

        // tower (normalized sum in A)
        float inv_pg = 1.f / (128 * HW);
        hipMemsetAsync(B, 0, (size_t)2 * 128 * g0.Psz * sizeof(bf16), stream);
        mconv(A, wrepT, nullptr, nullptr, nullptr, 0, B, 1, 0, g0.Psz, g0.Wp, 1, 8,
              flags, 2, 128, g0, 128, stream);
        float* sT = sp; sp += 4;
        run_stats(B, sT, 2, 128 * g0.Psz, stream);
        bf16* a = B; bf16* bb = A;
        for (int l = 1; l < 4; ++l) {
            Norm nm{sT, tow_gn_g, tow_gn_b, (size_t)(l - 1) * 128, 128, 1, inv_pg};
            mconv(a, wrepT + (size_t)l * 147456, &nm, nullptr, nullptr, 0,
                  bb, 1, 0, g0.Psz, g0.Wp, 1, 8, flags, 2, 128, g0, 128, stream);
            sT = sp; sp += 4;
            run_stats(bb, sT, 2, 128 * g0.Psz, stream);
            bf16* tmp = a; a = bb; bb = tmp;
        }
        // final tower raw in a (= A after 3 swaps), stats sT
        run_apply_pad(a, sT, tow_gn_g, tow_gn_b, (size_t)3 * 128, flags, 2, 128, 128, 1, g0, stream);
        conv1x1_k<<<(2 * 8 * HW + 255) / 256, 256, 0, stream>>>(
            a, out_w, flags, mfeat, 2, 128, 8, 96, 160, g0.Wp, g0.Psz);
        float* sM = sp; sp += 4;
        run_stats(mfeat, sM, 2, 8 * HW, stream);
        {
            long nvec = ((long)2 * 8 * HW) >> 3;
            gn_apply_v<<<(int)((nvec + 255) / 256), 256, 0, stream>>>(
                mfeat, sM, out_gn_g, out_gn_b, 0, flags, HW, 8, 8 * HW, 1.f / (8 * HW), nvec);
        }
        cast_out_k<<<(2 * 8 * HW + 255) / 256, 256, 0, stream>>>(
            mfeat, d_out, mf_off, flags, (long)2 * 8 * HW);
        dyn_conv_k<<<dim3((HW + 255) / 256, 200), 256, 0, stream>>>(mfeat, prm, dyn, 96, 160);
        long nt = (long)200 * 192 * 320;
        resize_out_k<<<(int)((nt + 255) / 256), 256, 0, stream>>>(
            dyn, d_out, ml_off, flags, 96, 160, 192, 320, nt);
    }
}